// Round 7
// baseline (501.280 us; speedup 1.0000x reference)
//
#include <hip/hip_runtime.h>
#include <stdint.h>

#define B_ 16
#define S_ 64
#define M_ 4096
#define D_ 1024
#define H_ 16
#define DH_ 64

typedef unsigned short ushort_t;
typedef __attribute__((ext_vector_type(8))) __bf16 bfrag;   // 8 bf16 = 4 VGPRs
typedef __attribute__((ext_vector_type(4))) float f32x4;

// fp32 -> bf16 RNE
__device__ __forceinline__ ushort_t f2bf(float f) {
  union { float f; uint32_t u; } v; v.f = f;
  uint32_t r = v.u + 0x7fffu + ((v.u >> 16) & 1u);
  return (ushort_t)(r >> 16);
}

__device__ __forceinline__ void gload_lds16(const void* g, void* l) {
  __builtin_amdgcn_global_load_lds((const __attribute__((address_space(1))) void*)g,
                                   (__attribute__((address_space(3))) void*)l, 16, 0, 0);
}

__device__ __forceinline__ f32x4 mfma16x16x32(bfrag a, bfrag b, f32x4 c) {
  return __builtin_amdgcn_mfma_f32_16x16x32_bf16(a, b, c, 0, 0, 0);
}

// epilogue-region swizzle: granule ^= fsw(row); fsw>>1 injective over klo groups
__device__ __forceinline__ int fsw(int r) { return (((r >> 2) & 3) << 1) | (r & 1); }

// ---------------- LayerNorm rows (1024 wide) -> bf16 ----------------
__global__ __launch_bounds__(256) void ln_rows_kernel(
    const float* __restrict__ x, const float* __restrict__ g,
    const float* __restrict__ bta, ushort_t* __restrict__ out) {
  const int row = blockIdx.x;
  const int t = threadIdx.x;
  const float4* xr = (const float4*)(x + (size_t)row * D_);
  float4 v = xr[t];
  float s = v.x + v.y + v.z + v.w;
  float ss = v.x * v.x + v.y * v.y + v.z * v.z + v.w * v.w;
#pragma unroll
  for (int o = 32; o >= 1; o >>= 1) { s += __shfl_down(s, o); ss += __shfl_down(ss, o); }
  __shared__ float red[16];
  const int wid = t >> 6;
  if ((t & 63) == 0) { red[wid] = s; red[8 + wid] = ss; }
  __syncthreads();
  float tot = red[0] + red[1] + red[2] + red[3];
  float tot2 = red[8] + red[9] + red[10] + red[11];
  float mu = tot * (1.0f / D_);
  float var = tot2 * (1.0f / D_) - mu * mu;
  float rstd = rsqrtf(var + 1e-5f);
  float4 gg = ((const float4*)g)[t];
  float4 bb = ((const float4*)bta)[t];
  ushort_t ob[4];
  ob[0] = f2bf((v.x - mu) * rstd * gg.x + bb.x);
  ob[1] = f2bf((v.y - mu) * rstd * gg.y + bb.y);
  ob[2] = f2bf((v.z - mu) * rstd * gg.z + bb.z);
  ob[3] = f2bf((v.w - mu) * rstd * gg.w + bb.w);
  *(uint2*)(out + (size_t)row * D_ + t * 4) = *(const uint2*)ob;
}

// ---------------- W[K=1024][N] fp32 -> WT[N][1024] bf16 (scaled) ----------------
__global__ void transpose_cast_kernel(const float* __restrict__ W, ushort_t* __restrict__ WT,
                                      int N, float scale) {
  __shared__ float tile[32][33];
  const int n0 = blockIdx.x * 32, k0 = blockIdx.y * 32;
  const int tx = threadIdx.x, ty = threadIdx.y;
#pragma unroll
  for (int i = ty; i < 32; i += 8)
    tile[i][tx] = W[(size_t)(k0 + i) * N + n0 + tx];
  __syncthreads();
#pragma unroll
  for (int i = ty; i < 32; i += 8)
    WT[(size_t)(n0 + i) * D_ + k0 + tx] = f2bf(tile[tx][i] * scale);
}

// ---------------- kv GEMM (small, 4.3 GF): 128x128, scatter to (b,h,s,d) ----------
__global__ __launch_bounds__(256) void gemm_kv_kernel(
    const ushort_t* __restrict__ A, const ushort_t* __restrict__ Bt,
    ushort_t* __restrict__ kb, ushort_t* __restrict__ vb) {
  __shared__ __align__(16) ushort_t sA[128 * 32];
  __shared__ __align__(16) ushort_t sB[128 * 32];
  const int tid = threadIdx.x, wid = tid >> 6, lane = tid & 63;
  const size_t arow0 = (size_t)blockIdx.x * 128;
  const size_t brow0 = (size_t)blockIdx.y * 128;
  const int wr = (wid >> 1) * 64, wc = (wid & 1) * 64;
  const int srow = tid >> 2, scol = (tid & 3) * 8;
  const ushort_t* ga = A + (arow0 + srow) * (size_t)D_ + scol;
  const ushort_t* gb = Bt + (brow0 + srow) * (size_t)D_ + scol;
  const int frow = lane & 15, kslot = (lane >> 4) * 8;
  f32x4 acc[4][4] = {};
  for (int k0 = 0; k0 < D_; k0 += 32) {
    gload_lds16(ga, sA + wid * 512);
    gload_lds16(ga + 64 * (size_t)D_, sA + 2048 + wid * 512);
    gload_lds16(gb, sB + wid * 512);
    gload_lds16(gb + 64 * (size_t)D_, sB + 2048 + wid * 512);
    ga += 32; gb += 32;
    __syncthreads();
    bfrag af[4], bfv[4];
#pragma unroll
    for (int m = 0; m < 4; ++m)
      af[m] = *(const bfrag*)&sA[(wr + m * 16 + frow) * 32 + kslot];
#pragma unroll
    for (int n = 0; n < 4; ++n)
      bfv[n] = *(const bfrag*)&sB[(wc + n * 16 + frow) * 32 + kslot];
#pragma unroll
    for (int m = 0; m < 4; ++m)
#pragma unroll
      for (int n = 0; n < 4; ++n)
        acc[m][n] = mfma16x16x32(af[m], bfv[n], acc[m][n]);
    __syncthreads();
  }
  const int erow = (lane >> 4) * 4, ecol = lane & 15;
#pragma unroll
  for (int m = 0; m < 4; ++m)
#pragma unroll
    for (int n = 0; n < 4; ++n)
#pragma unroll
      for (int r = 0; r < 4; ++r) {
        size_t i = arow0 + wr + m * 16 + erow + r;
        int bb = (int)(i >> 6), s = (int)(i & 63);
        size_t n2 = brow0 + wc + n * 16 + ecol;
        ushort_t val = f2bf(acc[m][n][r]);
        ushort_t* dst = (n2 < 1024) ? kb : vb;
        size_t hh = (n2 & 1023) >> 6, d = n2 & 63;
        dst[(((size_t)bb * H_ + hh) * S_ + s) * DH_ + d] = val;
      }
}

// ============== 256x128-tile GEMM, 4 waves, 2 blocks/CU, C = A * Bt^T =============
// The R3-R6 plateau (MfmaUtil ~33%) was CU-wide lockstep: one 8-wave/128KB block
// per CU, acc=128 AGPR capping 2 waves/SIMD -> LDS-read bursts and MFMA bursts
// strictly alternate with nothing to fill the gaps. Fix: 4-wave blocks @ 48KB LDS
// -> TWO independent blocks per CU (m114 overlap), counted vmcnt kept.
// Per ghalf (BK=32): vmcnt(6); s_barrier; 12 ds_read_b128 (compiler-scheduled
// lgkm waits); 32 MFMA (setprio); s_barrier; STAGE(g+2). Loads verified one full
// ghalf after issue; never vmcnt(0) in-loop.
// Grid 2048: chunked XCD map, 8 nblks of one mblk adjacent (A-panel L2 reuse).
// MODE 0: epilogue = fp32 C store; MODE 1: fused attention per wave-half.
template <int MODE>
__global__ __launch_bounds__(256, 2) void gemm128_kernel(
    const ushort_t* __restrict__ A, const ushort_t* __restrict__ Bt,
    const ushort_t* __restrict__ kbuf, const ushort_t* __restrict__ vbuf,
    void* __restrict__ Cout) {
  __shared__ __align__(16) ushort_t lds[24576];  // 48KB: A 2x16KB @0 | B 2x8KB @16384
  const int tid = threadIdx.x, wid = tid >> 6, lane = tid & 63;
  const int frow = lane & 15, klo = lane >> 4;
  const int wm = wid >> 1, wn = wid & 1;

  // chunked XCD mapping: 2048 blocks = 8 XCD chunks x 256; within chunk the 8
  // nblks of each mblk are consecutive -> A-panel (512KB) stays in the XCD's L2.
  const int l = ((int)blockIdx.x & 7) * 256 + ((int)blockIdx.x >> 3);
  const int mblk = l >> 3, nblk = l & 7;
  const size_t arow0 = (size_t)mblk * 256;
  const size_t bcol0 = (size_t)nblk * 128;

  // staging: thread covers (row r0 + j*64, granule gsrc), swizzle ^((row>>1)&3)
  const int r0 = tid >> 2;
  const int gsrc = (tid & 3) ^ ((tid >> 3) & 3);
  const ushort_t* pA = A + (arow0 + r0) * (size_t)D_ + gsrc * 8;
  const ushort_t* pB = Bt + (bcol0 + r0) * (size_t)D_ + gsrc * 8;
  const int rasw = (klo ^ ((frow >> 1) & 3)) * 8;

#define STAGE(G)                                                                   \
  do {                                                                             \
    const int s_ = (G) & 1;                                                        \
    const size_t ko_ = (size_t)((G) < 32 ? (G) : 31) * 32;                         \
    gload_lds16(pA + ko_, &lds[s_ * 8192 + wid * 512]);                            \
    gload_lds16(pA + 64 * (size_t)D_ + ko_, &lds[s_ * 8192 + 2048 + wid * 512]);   \
    gload_lds16(pA + 128 * (size_t)D_ + ko_, &lds[s_ * 8192 + 4096 + wid * 512]);  \
    gload_lds16(pA + 192 * (size_t)D_ + ko_, &lds[s_ * 8192 + 6144 + wid * 512]);  \
    gload_lds16(pB + ko_, &lds[16384 + s_ * 4096 + wid * 512]);                    \
    gload_lds16(pB + 64 * (size_t)D_ + ko_, &lds[16384 + s_ * 4096 + 2048 + wid * 512]); \
  } while (0)

  // prologue: ghalfs 0,1 (12 loads/thread)
  STAGE(0);
  STAGE(1);

  f32x4 acc[8][4] = {};
  for (int g = 0; g < 32; ++g) {
    // slot g ready when our 6 oldest loads retired; slot g+1 stays in flight
    asm volatile("s_waitcnt vmcnt(6)" ::: "memory");
    __builtin_amdgcn_s_barrier();
    asm volatile("" ::: "memory");
    const ushort_t* As = &lds[(g & 1) * 8192];
    const ushort_t* Bs = &lds[16384 + (g & 1) * 4096];
    bfrag a_[8], b_[4];
#pragma unroll
    for (int mf = 0; mf < 8; ++mf)
      a_[mf] = *(const bfrag*)&As[(wm * 128 + mf * 16 + frow) * 32 + rasw];
#pragma unroll
    for (int nf = 0; nf < 4; ++nf)
      b_[nf] = *(const bfrag*)&Bs[(wn * 64 + nf * 16 + frow) * 32 + rasw];
    __builtin_amdgcn_s_setprio(1);
#pragma unroll
    for (int mf = 0; mf < 8; ++mf)
#pragma unroll
      for (int nf = 0; nf < 4; ++nf)
        acc[mf][nf] = mfma16x16x32(a_[mf], b_[nf], acc[mf][nf]);
    __builtin_amdgcn_s_setprio(0);
    // all waves' reads of slot (g&1) retired once everyone arrives here
    asm volatile("" ::: "memory");
    __builtin_amdgcn_s_barrier();
    asm volatile("" ::: "memory");
    STAGE(g + 2);  // overwrite slot (g&1); tail re-stages ghalf 31 (harmless)
  }
  // drain tail stages before reusing LDS / exiting
  asm volatile("s_waitcnt vmcnt(0)" ::: "memory");
  __builtin_amdgcn_s_barrier();
  asm volatile("" ::: "memory");
#undef STAGE

  if constexpr (MODE == 0) {
    // ---------------- epilogue: fp32 C store (acc[m] rows = m*16 + klo*4 + r) -----
    float* C = (float*)Cout;
#pragma unroll
    for (int m = 0; m < 8; ++m)
#pragma unroll
      for (int n = 0; n < 4; ++n)
#pragma unroll
        for (int r = 0; r < 4; ++r)
          C[(arow0 + wm * 128 + m * 16 + klo * 4 + r) * 1024 + bcol0 + wn * 64 + n * 16 + frow] =
              acc[m][n][r];
  } else {
    // ---------------- epilogue: fused attention (wave-private) ----------------
    ushort_t* W = &lds[wid * 4096];  // [64][64] bf16, granule ^= fsw(row); ring is dead
    ushort_t* out1 = (ushort_t*)Cout;
    const int head = nblk * 2 + wn;
    const int bbatch = mblk >> 4;
    const size_t kvbase = ((size_t)bbatch * H_ + head) * (size_t)(S_ * DH_);
    bfrag kb[4][2], vb[4][2];
#pragma unroll
    for (int nf = 0; nf < 4; ++nf)
#pragma unroll
      for (int kk = 0; kk < 2; ++kk) {
        kb[nf][kk] = *(const bfrag*)&kbuf[kvbase + (nf * 16 + frow) * 64 + kk * 32 + klo * 8];
        vb[nf][kk] = *(const bfrag*)&vbuf[kvbase + (nf * 16 + frow) * 64 + kk * 32 + klo * 8];
      }
#pragma unroll
    for (int hh = 0; hh < 2; ++hh) {
      // q -> W (bf16, swizzled)
#pragma unroll
      for (int m2 = 0; m2 < 4; ++m2)
#pragma unroll
        for (int r = 0; r < 4; ++r) {
          const int row = m2 * 16 + klo * 4 + r;
          const int fs = fsw(row);
#pragma unroll
          for (int n = 0; n < 4; ++n) {
            const int cc = n * 16 + frow;
            W[row * 64 + ((((cc >> 3) ^ fs) << 3) | (cc & 7))] = f2bf(acc[hh * 4 + m2][n][r]);
          }
        }
      // sim = q @ K^T
      f32x4 s[4][4] = {};
#pragma unroll
      for (int m2 = 0; m2 < 4; ++m2) {
        const int row = m2 * 16 + frow;
        const int fs = fsw(row);
#pragma unroll
        for (int kk = 0; kk < 2; ++kk) {
          bfrag qa = *(const bfrag*)&W[row * 64 + (((kk * 4 + klo) ^ fs) << 3)];
#pragma unroll
          for (int nf = 0; nf < 4; ++nf)
            s[m2][nf] = mfma16x16x32(qa, kb[nf][kk], s[m2][nf]);
        }
      }
      // softmax over 64 keys (row in one 16-lane group, 4 keys/lane/frag)
#pragma unroll
      for (int m2 = 0; m2 < 4; ++m2)
#pragma unroll
        for (int r = 0; r < 4; ++r) {
          float a0 = s[m2][0][r], a1 = s[m2][1][r], a2 = s[m2][2][r], a3 = s[m2][3][r];
          float mx = fmaxf(fmaxf(a0, a1), fmaxf(a2, a3));
#pragma unroll
          for (int o = 1; o < 16; o <<= 1) mx = fmaxf(mx, __shfl_xor(mx, o));
          a0 = __expf(a0 - mx); a1 = __expf(a1 - mx);
          a2 = __expf(a2 - mx); a3 = __expf(a3 - mx);
          float sm = (a0 + a1) + (a2 + a3);
#pragma unroll
          for (int o = 1; o < 16; o <<= 1) sm += __shfl_xor(sm, o);
          const float inv = 1.0f / sm;
          s[m2][0][r] = a0 * inv; s[m2][1][r] = a1 * inv;
          s[m2][2][r] = a2 * inv; s[m2][3][r] = a3 * inv;
        }
      // P -> W (overwrite q; wave-private, in-order LDS)
#pragma unroll
      for (int m2 = 0; m2 < 4; ++m2)
#pragma unroll
        for (int r = 0; r < 4; ++r) {
          const int row = m2 * 16 + klo * 4 + r;
          const int fs = fsw(row);
#pragma unroll
          for (int n = 0; n < 4; ++n) {
            const int cc = n * 16 + frow;
            W[row * 64 + ((((cc >> 3) ^ fs) << 3) | (cc & 7))] = f2bf(s[m2][n][r]);
          }
        }
      // out1_half = attn @ "V^T" (einsum quirk: contract attn-keys with V dims)
      f32x4 o[4][4] = {};
#pragma unroll
      for (int m2 = 0; m2 < 4; ++m2) {
        const int row = m2 * 16 + frow;
        const int fs = fsw(row);
#pragma unroll
        for (int kk = 0; kk < 2; ++kk) {
          bfrag pa = *(const bfrag*)&W[row * 64 + (((kk * 4 + klo) ^ fs) << 3)];
#pragma unroll
          for (int nf = 0; nf < 4; ++nf)
            o[m2][nf] = mfma16x16x32(pa, vb[nf][kk], o[m2][nf]);
        }
      }
      // o -> W then coalesced uint4 stores
#pragma unroll
      for (int m2 = 0; m2 < 4; ++m2)
#pragma unroll
        for (int r = 0; r < 4; ++r) {
          const int row = m2 * 16 + klo * 4 + r;
          const int fs = fsw(row);
#pragma unroll
          for (int n = 0; n < 4; ++n) {
            const int cc = n * 16 + frow;
            W[row * 64 + ((((cc >> 3) ^ fs) << 3) | (cc & 7))] = f2bf(o[m2][n][r]);
          }
        }
      const size_t grow0 = arow0 + wm * 128 + hh * 64;
#pragma unroll
      for (int it = 0; it < 8; ++it) {
        const int idx = it * 64 + lane;
        const int rr = idx >> 3, gs = idx & 7;
        const int gcol = (gs ^ fsw(rr)) << 3;
        *(uint4*)&out1[(grow0 + rr) * 1024 + head * 64 + gcol] =
            *(const uint4*)&W[rr * 64 + gs * 8];
      }
    }
  }
}

// -------------------------------- launch --------------------------------
extern "C" void kernel_launch(void* const* d_in, const int* in_sizes, int n_in,
                              void* d_out, int out_size, void* d_ws, size_t ws_size,
                              hipStream_t stream) {
  const float* x = (const float*)d_in[0];
  const float* lat = (const float*)d_in[1];
  const float* lxg = (const float*)d_in[2];
  const float* lxb = (const float*)d_in[3];
  const float* llg = (const float*)d_in[4];
  const float* llb = (const float*)d_in[5];
  const float* Wq = (const float*)d_in[6];
  const float* Wkv = (const float*)d_in[7];
  const float* Wout = (const float*)d_in[8];
  float* out = (float*)d_out;
  char* ws = (char*)d_ws;

  // ws layout (142MB): xn 2MB | wqT 2MB | wkvT 4MB | woT 2MB | k 2MB | v 2MB | out1 128MB
  ushort_t* xn = (ushort_t*)(ws);
  ushort_t* wqT = (ushort_t*)(ws + (2ull << 20));
  ushort_t* wkvT = (ushort_t*)(ws + (4ull << 20));
  ushort_t* woT = (ushort_t*)(ws + (8ull << 20));
  ushort_t* kbuf = (ushort_t*)(ws + (10ull << 20));
  ushort_t* vbuf = (ushort_t*)(ws + (12ull << 20));
  ushort_t* out1 = (ushort_t*)(ws + (14ull << 20));
  // lnl (bf16, 128MB) lives in d_out's first half: dead before final GEMM writes d_out
  ushort_t* lnl = (ushort_t*)d_out;

  dim3 tb(32, 8);
  transpose_cast_kernel<<<dim3(1024 / 32, 32), tb, 0, stream>>>(Wq, wqT, 1024, 0.125f);
  transpose_cast_kernel<<<dim3(2048 / 32, 32), tb, 0, stream>>>(Wkv, wkvT, 2048, 1.0f);
  transpose_cast_kernel<<<dim3(1024 / 32, 32), tb, 0, stream>>>(Wout, woT, 1024, 1.0f);
  ln_rows_kernel<<<B_ * S_, 256, 0, stream>>>(x, lxg, lxb, xn);
  ln_rows_kernel<<<B_ * M_, 256, 0, stream>>>(lat, llg, llb, lnl);
  gemm_kv_kernel<<<dim3(8, 16), 256, 0, stream>>>(xn, wkvT, kbuf, vbuf);
  gemm128_kernel<1><<<2048, 256, 0, stream>>>(lnl, wqT, kbuf, vbuf, out1);
  gemm128_kernel<0><<<2048, 256, 0, stream>>>(out1, woT, nullptr, nullptr, out);
}

// Round 8
// 476.871 us; speedup vs baseline: 1.0512x; 1.0512x over previous
//
#include <hip/hip_runtime.h>
#include <stdint.h>

#define B_ 16
#define S_ 64
#define M_ 4096
#define D_ 1024
#define H_ 16
#define DH_ 64

typedef unsigned short ushort_t;
typedef __attribute__((ext_vector_type(8))) __bf16 bfrag;   // 8 bf16 = 4 VGPRs
typedef __attribute__((ext_vector_type(4))) float f32x4;
typedef __attribute__((ext_vector_type(4))) uint32_t u32x4;

// fp32 -> bf16 RNE
__device__ __forceinline__ ushort_t f2bf(float f) {
  union { float f; uint32_t u; } v; v.f = f;
  uint32_t r = v.u + 0x7fffu + ((v.u >> 16) & 1u);
  return (ushort_t)(r >> 16);
}

__device__ __forceinline__ void gload_lds16(const void* g, void* l) {
  __builtin_amdgcn_global_load_lds((const __attribute__((address_space(1))) void*)g,
                                   (__attribute__((address_space(3))) void*)l, 16, 0, 0);
}

// inline-asm LDS read: invisible to the compiler's DMA-alias tracking, so it
// cannot trigger an implicit s_waitcnt vmcnt(0) before the read cluster.
// Caller MUST wait lgkmcnt(0) + sched_barrier(0) before consuming (rule #18).
__device__ __forceinline__ bfrag ds_read128(const ushort_t* p) {
  u32x4 r;
  uint32_t a = (uint32_t)(uintptr_t)(const __attribute__((address_space(3))) ushort_t*)p;
  asm volatile("ds_read_b128 %0, %1" : "=v"(r) : "v"(a));
  union { u32x4 u; bfrag b; } c;
  c.u = r;
  return c.b;
}

__device__ __forceinline__ f32x4 mfma16x16x32(bfrag a, bfrag b, f32x4 c) {
  return __builtin_amdgcn_mfma_f32_16x16x32_bf16(a, b, c, 0, 0, 0);
}

// epilogue-region swizzle: granule ^= fsw(row); fsw>>1 injective over klo groups
__device__ __forceinline__ int fsw(int r) { return (((r >> 2) & 3) << 1) | (r & 1); }

// ---------------- LayerNorm rows (1024 wide) -> bf16 ----------------
__global__ __launch_bounds__(256) void ln_rows_kernel(
    const float* __restrict__ x, const float* __restrict__ g,
    const float* __restrict__ bta, ushort_t* __restrict__ out) {
  const int row = blockIdx.x;
  const int t = threadIdx.x;
  const float4* xr = (const float4*)(x + (size_t)row * D_);
  float4 v = xr[t];
  float s = v.x + v.y + v.z + v.w;
  float ss = v.x * v.x + v.y * v.y + v.z * v.z + v.w * v.w;
#pragma unroll
  for (int o = 32; o >= 1; o >>= 1) { s += __shfl_down(s, o); ss += __shfl_down(ss, o); }
  __shared__ float red[16];
  const int wid = t >> 6;
  if ((t & 63) == 0) { red[wid] = s; red[8 + wid] = ss; }
  __syncthreads();
  float tot = red[0] + red[1] + red[2] + red[3];
  float tot2 = red[8] + red[9] + red[10] + red[11];
  float mu = tot * (1.0f / D_);
  float var = tot2 * (1.0f / D_) - mu * mu;
  float rstd = rsqrtf(var + 1e-5f);
  float4 gg = ((const float4*)g)[t];
  float4 bb = ((const float4*)bta)[t];
  ushort_t ob[4];
  ob[0] = f2bf((v.x - mu) * rstd * gg.x + bb.x);
  ob[1] = f2bf((v.y - mu) * rstd * gg.y + bb.y);
  ob[2] = f2bf((v.z - mu) * rstd * gg.z + bb.z);
  ob[3] = f2bf((v.w - mu) * rstd * gg.w + bb.w);
  *(uint2*)(out + (size_t)row * D_ + t * 4) = *(const uint2*)ob;
}

// ---------------- W[K=1024][N] fp32 -> WT[N][1024] bf16 (scaled) ----------------
__global__ void transpose_cast_kernel(const float* __restrict__ W, ushort_t* __restrict__ WT,
                                      int N, float scale) {
  __shared__ float tile[32][33];
  const int n0 = blockIdx.x * 32, k0 = blockIdx.y * 32;
  const int tx = threadIdx.x, ty = threadIdx.y;
#pragma unroll
  for (int i = ty; i < 32; i += 8)
    tile[i][tx] = W[(size_t)(k0 + i) * N + n0 + tx];
  __syncthreads();
#pragma unroll
  for (int i = ty; i < 32; i += 8)
    WT[(size_t)(n0 + i) * D_ + k0 + tx] = f2bf(tile[tx][i] * scale);
}

// ---------------- kv GEMM (small, 4.3 GF): 128x128, scatter to (b,h,s,d) ----------
__global__ __launch_bounds__(256) void gemm_kv_kernel(
    const ushort_t* __restrict__ A, const ushort_t* __restrict__ Bt,
    ushort_t* __restrict__ kb, ushort_t* __restrict__ vb) {
  __shared__ __align__(16) ushort_t sA[128 * 32];
  __shared__ __align__(16) ushort_t sB[128 * 32];
  const int tid = threadIdx.x, wid = tid >> 6, lane = tid & 63;
  const size_t arow0 = (size_t)blockIdx.x * 128;
  const size_t brow0 = (size_t)blockIdx.y * 128;
  const int wr = (wid >> 1) * 64, wc = (wid & 1) * 64;
  const int srow = tid >> 2, scol = (tid & 3) * 8;
  const ushort_t* ga = A + (arow0 + srow) * (size_t)D_ + scol;
  const ushort_t* gb = Bt + (brow0 + srow) * (size_t)D_ + scol;
  const int frow = lane & 15, kslot = (lane >> 4) * 8;
  f32x4 acc[4][4] = {};
  for (int k0 = 0; k0 < D_; k0 += 32) {
    gload_lds16(ga, sA + wid * 512);
    gload_lds16(ga + 64 * (size_t)D_, sA + 2048 + wid * 512);
    gload_lds16(gb, sB + wid * 512);
    gload_lds16(gb + 64 * (size_t)D_, sB + 2048 + wid * 512);
    ga += 32; gb += 32;
    __syncthreads();
    bfrag af[4], bfv[4];
#pragma unroll
    for (int m = 0; m < 4; ++m)
      af[m] = *(const bfrag*)&sA[(wr + m * 16 + frow) * 32 + kslot];
#pragma unroll
    for (int n = 0; n < 4; ++n)
      bfv[n] = *(const bfrag*)&sB[(wc + n * 16 + frow) * 32 + kslot];
#pragma unroll
    for (int m = 0; m < 4; ++m)
#pragma unroll
      for (int n = 0; n < 4; ++n)
        acc[m][n] = mfma16x16x32(af[m], bfv[n], acc[m][n]);
    __syncthreads();
  }
  const int erow = (lane >> 4) * 4, ecol = lane & 15;
#pragma unroll
  for (int m = 0; m < 4; ++m)
#pragma unroll
    for (int n = 0; n < 4; ++n)
#pragma unroll
      for (int r = 0; r < 4; ++r) {
        size_t i = arow0 + wr + m * 16 + erow + r;
        int bb = (int)(i >> 6), s = (int)(i & 63);
        size_t n2 = brow0 + wc + n * 16 + ecol;
        ushort_t val = f2bf(acc[m][n][r]);
        ushort_t* dst = (n2 < 1024) ? kb : vb;
        size_t hh = (n2 & 1023) >> 6, d = n2 & 63;
        dst[(((size_t)bb * H_ + hh) * S_ + s) * DH_ + d] = val;
      }
}

// ============== 256x256 ring GEMM with ASM ds_read (no implicit drains) ===========
// ghalf g = K cols [g*32,g*32+32); 16KB slot; 4-slot ring/operand; 128KB LDS.
// 8 waves (2m x 4n), per-wave 128x64 out. Per ghalf, ONE barrier:
//   { vmcnt(8); s_barrier; STAGE(g+3); 12x asm ds_read_b128; lgkmcnt(0);
//     sched_barrier; 32 MFMA (setprio); sched_barrier }
// vmcnt(8): per-thread 4 loads/ghalf, 3-ghalf prologue => oldest-but-8 retired
// == tile g landed (3-ghalf / ~3000cyc lead). asm ds_read is invisible to the
// compiler's DMA-alias model -> no compiler-inserted vmcnt(0) per phase (the
// R3-R7 ~660TF plateau). lgkmcnt(0) before MFMA => reads complete before each
// wave hits the next barrier => single barrier suffices for WAR on the ring.
// MODE 0: epilogue = fp32 C store; MODE 1: fused attention per wave-half.
template <int MODE>
__global__ __launch_bounds__(512, 2) void gemm256_kernel(
    const ushort_t* __restrict__ A, const ushort_t* __restrict__ Bt,
    const ushort_t* __restrict__ kbuf, const ushort_t* __restrict__ vbuf,
    void* __restrict__ Cout) {
  __shared__ __align__(16) ushort_t lds[65536];  // 128KB: A ring 64KB | B ring 64KB
  const int tid = threadIdx.x, wid = tid >> 6, lane = tid & 63;
  const int frow = lane & 15, klo = lane >> 4;
  const int wm = wid >> 2, wn = wid & 3;

  // XCD-swizzled block mapping (1024 = 8*128, bijective)
  const int l = ((int)blockIdx.x & 7) * 128 + ((int)blockIdx.x >> 3);
  const int mblk = l >> 2, nblk = l & 3;
  const size_t arow0 = (size_t)mblk * 256;
  const size_t bcol0 = (size_t)nblk * 256;

  // staging: thread covers (row r0, granule gsrc), swizzle ^((row>>1)&3)
  const int r0 = tid >> 2;                       // 0..127
  const int gsrc = (tid & 3) ^ ((tid >> 3) & 3);
  const ushort_t* pA0 = A + (arow0 + r0) * (size_t)D_ + gsrc * 8;
  const ushort_t* pA1 = pA0 + (size_t)128 * D_;
  const ushort_t* pB0 = Bt + (bcol0 + r0) * (size_t)D_ + gsrc * 8;
  const ushort_t* pB1 = pB0 + (size_t)128 * D_;
  // ds_read swizzled granule offset (ushort units; row bits1-2 == frow bits1-2)
  const int rasw = (klo ^ ((frow >> 1) & 3)) * 8;

#define STAGE(G)                                                              \
  do {                                                                        \
    const int s_ = (G) & 3;                                                   \
    const size_t ko_ = (size_t)((G) < 32 ? (G) : 31) * 32;                    \
    gload_lds16(pA0 + ko_, &lds[s_ * 8192 + wid * 512]);                      \
    gload_lds16(pA1 + ko_, &lds[s_ * 8192 + 4096 + wid * 512]);               \
    gload_lds16(pB0 + ko_, &lds[32768 + s_ * 8192 + wid * 512]);              \
    gload_lds16(pB1 + ko_, &lds[32768 + s_ * 8192 + 4096 + wid * 512]);       \
  } while (0)

  // prologue: ghalfs 0,1,2 (12 loads/thread outstanding)
  STAGE(0);
  STAGE(1);
  STAGE(2);

  // per-lane constant ushort offsets within a slot
  const int aoff = wm * 4096 + frow * 32 + rasw;                 // + mf*512
  const int boff = (wn >> 1) * 4096 + ((wn & 1) * 64 + frow) * 32 + rasw;  // + nf*512

  f32x4 acc[8][4] = {};
  for (int g = 0; g < 32; ++g) {
    asm volatile("s_waitcnt vmcnt(8)" ::: "memory");
    __builtin_amdgcn_s_barrier();
    STAGE(g + 3);  // slot (g-1)&3: all waves' reads of it completed before this barrier
    const int sb = (g & 3) * 8192;
    bfrag a_[8], b_[4];
#pragma unroll
    for (int mf = 0; mf < 8; ++mf)
      a_[mf] = ds_read128(&lds[sb + aoff + mf * 512]);
#pragma unroll
    for (int nf = 0; nf < 4; ++nf)
      b_[nf] = ds_read128(&lds[32768 + sb + boff + nf * 512]);
    asm volatile("s_waitcnt lgkmcnt(0)" ::: "memory");
    __builtin_amdgcn_sched_barrier(0);
    __builtin_amdgcn_s_setprio(1);
#pragma unroll
    for (int mf = 0; mf < 8; ++mf)
#pragma unroll
      for (int nf = 0; nf < 4; ++nf)
        acc[mf][nf] = mfma16x16x32(a_[mf], b_[nf], acc[mf][nf]);
    __builtin_amdgcn_s_setprio(0);
    __builtin_amdgcn_sched_barrier(0);  // keep MFMAs in-phase
  }
  // drain tail garbage-stages before reusing LDS / exiting
  asm volatile("s_waitcnt vmcnt(0)" ::: "memory");
  __builtin_amdgcn_s_barrier();
  __builtin_amdgcn_sched_barrier(0);
#undef STAGE

  if constexpr (MODE == 0) {
    // ---------------- epilogue: fp32 C store (acc[m] rows = m*16 + klo*4 + r) -----
    float* C = (float*)Cout;
#pragma unroll
    for (int m = 0; m < 8; ++m)
#pragma unroll
      for (int n = 0; n < 4; ++n)
#pragma unroll
        for (int r = 0; r < 4; ++r)
          C[(arow0 + wm * 128 + m * 16 + klo * 4 + r) * 1024 + bcol0 + wn * 64 + n * 16 + frow] =
              acc[m][n][r];
  } else {
    // ---------------- epilogue: fused attention (wave-private) ----------------
    ushort_t* W = &lds[wid * 4096];  // [64][64] bf16, granule ^= fsw(row); ring is dead
    ushort_t* out1 = (ushort_t*)Cout;
    const int head = nblk * 4 + wn;
    const int bbatch = mblk >> 4;
    const size_t kvbase = ((size_t)bbatch * H_ + head) * (size_t)(S_ * DH_);
    bfrag kb[4][2], vb[4][2];
#pragma unroll
    for (int nf = 0; nf < 4; ++nf)
#pragma unroll
      for (int kk = 0; kk < 2; ++kk) {
        kb[nf][kk] = *(const bfrag*)&kbuf[kvbase + (nf * 16 + frow) * 64 + kk * 32 + klo * 8];
        vb[nf][kk] = *(const bfrag*)&vbuf[kvbase + (nf * 16 + frow) * 64 + kk * 32 + klo * 8];
      }
#pragma unroll
    for (int hh = 0; hh < 2; ++hh) {
      // q -> W (bf16, swizzled)
#pragma unroll
      for (int m2 = 0; m2 < 4; ++m2)
#pragma unroll
        for (int r = 0; r < 4; ++r) {
          const int row = m2 * 16 + klo * 4 + r;
          const int fs = fsw(row);
#pragma unroll
          for (int n = 0; n < 4; ++n) {
            const int cc = n * 16 + frow;
            W[row * 64 + ((((cc >> 3) ^ fs) << 3) | (cc & 7))] = f2bf(acc[hh * 4 + m2][n][r]);
          }
        }
      // sim = q @ K^T
      f32x4 s[4][4] = {};
#pragma unroll
      for (int m2 = 0; m2 < 4; ++m2) {
        const int row = m2 * 16 + frow;
        const int fs = fsw(row);
#pragma unroll
        for (int kk = 0; kk < 2; ++kk) {
          bfrag qa = *(const bfrag*)&W[row * 64 + (((kk * 4 + klo) ^ fs) << 3)];
#pragma unroll
          for (int nf = 0; nf < 4; ++nf)
            s[m2][nf] = mfma16x16x32(qa, kb[nf][kk], s[m2][nf]);
        }
      }
      // softmax over 64 keys (row in one 16-lane group, 4 keys/lane/frag)
#pragma unroll
      for (int m2 = 0; m2 < 4; ++m2)
#pragma unroll
        for (int r = 0; r < 4; ++r) {
          float a0 = s[m2][0][r], a1 = s[m2][1][r], a2 = s[m2][2][r], a3 = s[m2][3][r];
          float mx = fmaxf(fmaxf(a0, a1), fmaxf(a2, a3));
#pragma unroll
          for (int o = 1; o < 16; o <<= 1) mx = fmaxf(mx, __shfl_xor(mx, o));
          a0 = __expf(a0 - mx); a1 = __expf(a1 - mx);
          a2 = __expf(a2 - mx); a3 = __expf(a3 - mx);
          float sm = (a0 + a1) + (a2 + a3);
#pragma unroll
          for (int o = 1; o < 16; o <<= 1) sm += __shfl_xor(sm, o);
          const float inv = 1.0f / sm;
          s[m2][0][r] = a0 * inv; s[m2][1][r] = a1 * inv;
          s[m2][2][r] = a2 * inv; s[m2][3][r] = a3 * inv;
        }
      // P -> W (overwrite q; wave-private, in-order LDS)
#pragma unroll
      for (int m2 = 0; m2 < 4; ++m2)
#pragma unroll
        for (int r = 0; r < 4; ++r) {
          const int row = m2 * 16 + klo * 4 + r;
          const int fs = fsw(row);
#pragma unroll
          for (int n = 0; n < 4; ++n) {
            const int cc = n * 16 + frow;
            W[row * 64 + ((((cc >> 3) ^ fs) << 3) | (cc & 7))] = f2bf(s[m2][n][r]);
          }
        }
      // out1_half = attn @ "V^T" (einsum quirk: contract attn-keys with V dims)
      f32x4 o[4][4] = {};
#pragma unroll
      for (int m2 = 0; m2 < 4; ++m2) {
        const int row = m2 * 16 + frow;
        const int fs = fsw(row);
#pragma unroll
        for (int kk = 0; kk < 2; ++kk) {
          bfrag pa = *(const bfrag*)&W[row * 64 + (((kk * 4 + klo) ^ fs) << 3)];
#pragma unroll
          for (int nf = 0; nf < 4; ++nf)
            o[m2][nf] = mfma16x16x32(pa, vb[nf][kk], o[m2][nf]);
        }
      }
      // o -> W then coalesced uint4 stores
#pragma unroll
      for (int m2 = 0; m2 < 4; ++m2)
#pragma unroll
        for (int r = 0; r < 4; ++r) {
          const int row = m2 * 16 + klo * 4 + r;
          const int fs = fsw(row);
#pragma unroll
          for (int n = 0; n < 4; ++n) {
            const int cc = n * 16 + frow;
            W[row * 64 + ((((cc >> 3) ^ fs) << 3) | (cc & 7))] = f2bf(o[m2][n][r]);
          }
        }
      const size_t grow0 = arow0 + wm * 128 + hh * 64;
#pragma unroll
      for (int it = 0; it < 8; ++it) {
        const int idx = it * 64 + lane;
        const int rr = idx >> 3, gs = idx & 7;
        const int gcol = (gs ^ fsw(rr)) << 3;
        *(uint4*)&out1[(grow0 + rr) * 1024 + head * 64 + gcol] =
            *(const uint4*)&W[rr * 64 + gs * 8];
      }
    }
  }
}

// -------------------------------- launch --------------------------------
extern "C" void kernel_launch(void* const* d_in, const int* in_sizes, int n_in,
                              void* d_out, int out_size, void* d_ws, size_t ws_size,
                              hipStream_t stream) {
  const float* x = (const float*)d_in[0];
  const float* lat = (const float*)d_in[1];
  const float* lxg = (const float*)d_in[2];
  const float* lxb = (const float*)d_in[3];
  const float* llg = (const float*)d_in[4];
  const float* llb = (const float*)d_in[5];
  const float* Wq = (const float*)d_in[6];
  const float* Wkv = (const float*)d_in[7];
  const float* Wout = (const float*)d_in[8];
  float* out = (float*)d_out;
  char* ws = (char*)d_ws;

  // ws layout (142MB): xn 2MB | wqT 2MB | wkvT 4MB | woT 2MB | k 2MB | v 2MB | out1 128MB
  ushort_t* xn = (ushort_t*)(ws);
  ushort_t* wqT = (ushort_t*)(ws + (2ull << 20));
  ushort_t* wkvT = (ushort_t*)(ws + (4ull << 20));
  ushort_t* woT = (ushort_t*)(ws + (8ull << 20));
  ushort_t* kbuf = (ushort_t*)(ws + (10ull << 20));
  ushort_t* vbuf = (ushort_t*)(ws + (12ull << 20));
  ushort_t* out1 = (ushort_t*)(ws + (14ull << 20));
  // lnl (bf16, 128MB) lives in d_out's first half: dead before final GEMM writes d_out
  ushort_t* lnl = (ushort_t*)d_out;

  dim3 tb(32, 8);
  transpose_cast_kernel<<<dim3(1024 / 32, 32), tb, 0, stream>>>(Wq, wqT, 1024, 0.125f);
  transpose_cast_kernel<<<dim3(2048 / 32, 32), tb, 0, stream>>>(Wkv, wkvT, 2048, 1.0f);
  transpose_cast_kernel<<<dim3(1024 / 32, 32), tb, 0, stream>>>(Wout, woT, 1024, 1.0f);
  ln_rows_kernel<<<B_ * S_, 256, 0, stream>>>(x, lxg, lxb, xn);
  ln_rows_kernel<<<B_ * M_, 256, 0, stream>>>(lat, llg, llb, lnl);
  gemm_kv_kernel<<<dim3(8, 16), 256, 0, stream>>>(xn, wkvT, kbuf, vbuf);
  gemm256_kernel<1><<<1024, 512, 0, stream>>>(lnl, wqT, kbuf, vbuf, out1);
  gemm256_kernel<0><<<1024, 512, 0, stream>>>(out1, woT, nullptr, nullptr, out);
}